// Round 9
// baseline (40.673 us; speedup 1.0000x reference)
//
#include <hip/hip_runtime.h>

// ECT: out[b,c,r,t] = sum_{n in (b,c)} sigmoid(SCALE*(lin[r] - x[n].v[:,t])), max-normalized per (b,c).
// ROUND 8 = INSTRUMENTED CHAMPION (r3 structure, 18.1us): the accumulation body runs 4x.
// Normalization out=ect/amax cancels the uniform 4x, so output is unchanged (absmax ~0.004),
// but the kernel becomes long enough (>39us) to appear in rocprof top-5 WITH counters.
// FPSCALE lowered 2^20 -> 2^18 so 4x accumulation cannot overflow u32.

constexpr int T   = 64;
constexpr int RES = 64;
constexpr float RADIUS = 1.0f;
constexpr float SCALE  = 100.0f;
constexpr float LOG2E  = 1.44269504088896340736f;

#define THREADS 1024
#define WAVES   16
#define CHUNK   1024
#define NB      4                  // exact window bins
#define PAD     5                  // sig index = r + PAD, r in [-5, 68] -> stride 75
#define SSTR    75
#define HSTR    66
#define TK      512                // table rows (fractional-position quantization)
#define NREP    4                  // diagnostic repetition (cancelled by normalization)
#define FPSCALE 262144.0f          // 2^18 (4 reps * 1024 pts * 2^18 = 2^30 < 2^32)
#define FPINV   (1.0f / 262144.0f)

__global__ __launch_bounds__(THREADS) void ect_main(
    const float* __restrict__ x, const float* __restrict__ v,
    const int* __restrict__ index, const int* __restrict__ channels,
    float* __restrict__ out, int N)
{
  __shared__ alignas(16) float    lx[4160];        // compacted points / reused as fin[64][65]
  __shared__ alignas(16) unsigned tbl[TK * NB];    // quantized sigmoid window table (8KB)
  __shared__ unsigned sig[T * SSTR];               // fixed-point window accumulator [t][r+PAD]
  __shared__ unsigned hist[T * HSTR];              // tail histogram [t][0..64]
  __shared__ int      l_bounds[2];
  __shared__ int      l_cnt;
  __shared__ float    wmax[WAVES];
  __shared__ float    s_scale;

  const int seg  = blockIdx.x;
  const int b    = seg >> 2;     // MAX_CHANNELS == 4
  const int c    = seg & 3;
  const int tid  = threadIdx.x;
  const int lane = tid & 63;
  const int wv   = tid >> 6;

  const float S2D  = SCALE * LOG2E * (2.0f * RADIUS / (RES - 1));  // log2-domain arg step per bin
  const float invD = (RES - 1) / (2.0f * RADIUS);                  // 31.5

  for (int i = tid; i < T * SSTR; i += THREADS) sig[i]  = 0u;
  for (int i = tid; i < T * HSTR; i += THREADS) hist[i] = 0u;

  // window table: tbl[q][u] = round(FPSCALE * sigmoid(S2D*((u-1) - f))), f=(q+0.5)/TK
  for (int i = tid; i < TK * NB; i += THREADS) {
    int   q = i >> 2, u = i & 3;
    float f = (q + 0.5f) * (1.0f / TK);
    float e = __builtin_amdgcn_exp2f(S2D * (1.0f + f - (float)u));
    float s = 1.0f / (1.0f + e);
    tbl[i] = (unsigned)(s * FPSCALE + 0.5f);
  }

  // wave-parallel 64-ary search for batch bounds (waves 14,15)
  if (wv >= 14) {
    const int tg = b + (wv - 14);
    int lo = 0, len = N;
    while (len > 64) {
      int step = (len + 63) >> 6;
      int p = lo + lane * step;
      bool lt = (p < lo + len) && (index[p] < tg);
      unsigned long long mask = __ballot(lt);
      if (mask) lo += (63 - __clzll(mask)) * step + 1;
      len = min(step, N - lo);
    }
    int p = lo + lane;
    bool ge = (lane < len) && (index[p] >= tg);
    unsigned long long mask = __ballot(ge);
    int ans = mask ? (lo + (int)__builtin_ctzll(mask)) : (lo + len);
    if (lane == 0) l_bounds[wv - 14] = ans;
  }
  __syncthreads();
  const int s0 = l_bounds[0], s1 = l_bounds[1];

  const float v0 = v[0 * T + lane], v1 = v[1 * T + lane], v2 = v[2 * T + lane];
  unsigned* const srow0 = &sig[lane * SSTR];
  unsigned* const hrow0 = &hist[lane * HSTR];

  for (int rep = 0; rep < NREP; ++rep) {           // diagnostic 4x (normalization cancels it)
    for (int base = s0; base < s1; base += CHUNK) {
      const int cnt = min(CHUNK, s1 - base);
      if (tid == 0) l_cnt = 0;
      __syncthreads();
      // ballot-compact channel-c points into lx
      if (tid < cnt) {
        const int pt = base + tid;
        const bool match = (channels[pt] == c);
        unsigned long long mask = __ballot(match);
        int wcnt = __popcll(mask);
        int pos = 0;
        if (lane == 0 && wcnt) pos = atomicAdd(&l_cnt, wcnt);
        pos = __shfl(pos, 0);
        if (match) {
          int off = pos + __popcll(mask & ((1ull << lane) - 1ull));
          lx[off * 4 + 0] = x[pt * 3 + 0];
          lx[off * 4 + 1] = x[pt * 3 + 1];
          lx[off * 4 + 2] = x[pt * 3 + 2];
        }
      }
      __syncthreads();
      const int m = l_cnt;
      const float4* lx4 = (const float4*)lx;

      // waves stripe points; lane = t; 2-deep pipelined point prefetch
      int j = wv;
      if (j < m) {
        float4 p = lx4[j];
        for (;;) {
          int jn = j + WAVES;
          float4 pn;
          if (jn < m) pn = lx4[jn];
          const float nh = p.x * v0 + p.y * v1 + p.z * v2;
          const float g  = fmaf(nh, invD, invD);     // (nh + 1) * 31.5
          const float gf = floorf(g);
          const float f  = g - gf;
          const int   fq = (int)(f * (float)TK);
          const int   lo = (int)gf - 1;
          const int   lc = min(max(lo, -PAD), RES);
          const uint4 tv = *(const uint4*)&tbl[fq << 2];
          unsigned* srow = srow0 + (lc + PAD);
          atomicAdd(&srow[0], tv.x);
          atomicAdd(&srow[1], tv.y);
          atomicAdd(&srow[2], tv.z);
          atomicAdd(&srow[3], tv.w);
          const int ci = min(max(lo + NB, 0), RES);
          atomicAdd(&hrow0[ci], 1u);
          if (jn >= m) break;
          j = jn;
          p = pn;
        }
      }
      __syncthreads();
    }
  }

  // per-t inclusive prefix over r of hist, combine with window sums -> fin (reuses lx, stride 65)
  float* fin = lx;
  #pragma unroll
  for (int u2 = 0; u2 < 4; ++u2) {
    const int t = (wv << 2) | u2;
    unsigned h = hist[t * HSTR + lane];            // lane = r
    #pragma unroll
    for (int d = 1; d < 64; d <<= 1) {
      unsigned o = __shfl_up(h, (unsigned)d);
      if (lane >= d) h += o;
    }
    fin[lane * 65 + t] = (float)sig[t * SSTR + (lane + PAD)] * FPINV + (float)h;
  }
  __syncthreads();

  // block max-reduce + normalize + coalesced store
  float vals[4];
  float mx = 0.0f;
  #pragma unroll
  for (int k = 0; k < 4; ++k) {
    const int r = wv + k * 16;                     // flat = tid + k*1024 -> r, t = lane
    vals[k] = fin[r * 65 + lane];
    mx = fmaxf(mx, vals[k]);
  }
  #pragma unroll
  for (int s = 32; s >= 1; s >>= 1) mx = fmaxf(mx, __shfl_xor(mx, s));
  if (lane == 0) wmax[wv] = mx;
  __syncthreads();
  if (tid == 0) {
    float m2 = wmax[0];
    #pragma unroll
    for (int i = 1; i < WAVES; ++i) m2 = fmaxf(m2, wmax[i]);
    s_scale = (m2 > 0.0f) ? 1.0f / m2 : 1.0f;
  }
  __syncthreads();
  const float sc = s_scale;
  float* o = out + (size_t)seg * (RES * T);
  #pragma unroll
  for (int k = 0; k < 4; ++k) o[tid + k * THREADS] = vals[k] * sc;
}

extern "C" void kernel_launch(void* const* d_in, const int* in_sizes, int n_in,
                              void* d_out, int out_size, void* d_ws, size_t ws_size,
                              hipStream_t stream) {
  const float* x        = (const float*)d_in[0];
  const float* v        = (const float*)d_in[1];
  const int*   index    = (const int*)d_in[2];
  const int*   channels = (const int*)d_in[3];
  float*       out      = (float*)d_out;
  const int N    = in_sizes[2];              // 32768
  const int nseg = out_size / (RES * T);     // 128

  hipLaunchKernelGGL(ect_main, dim3(nseg), dim3(THREADS), 0, stream,
                     x, v, index, channels, out, N);
}

// Round 10
// 17.005 us; speedup vs baseline: 2.3918x; 2.3918x over previous
//
#include <hip/hip_runtime.h>

// ECT: out[b,c,r,t] = sum_{n in (b,c)} sigmoid(SCALE*(lin[r] - x[n].v[:,t])), max-normalized per (b,c).
// r9: champion r3 structure, hot loop rebuilt from r8's counter evidence (LDS-pipe bound, 4.2M
// conflict cycles): table gather ELIMINATED (exp2+rcp on the 87%-idle VALU/trans pipe), separate
// hist ELIMINATED via delta encoding (5 ds_add_u32/point: d0..d3 + tail; prefix over r rebuilds).

constexpr int T   = 64;
constexpr int RES = 64;
constexpr float RADIUS = 1.0f;
constexpr float SCALE  = 100.0f;
constexpr float LOG2E  = 1.44269504088896340736f;

#define THREADS 1024
#define WAVES   16
#define CHUNK   1536               // > max batch len (~1100) -> chunk loop runs once
#define NROWS   69                 // delta rows 0..68 (lo in [-4,64], tail at lo+4)
#define FPSCALE 1048576.0f         // 2^20
#define FPQ     1048576u
#define FPINV   (1.0f / 1048576.0f)

__global__ __launch_bounds__(THREADS) void ect_main(
    const float* __restrict__ x, const float* __restrict__ v,
    const int* __restrict__ index, const int* __restrict__ channels,
    float* __restrict__ out, int N)
{
  __shared__ alignas(16) float lx[CHUNK * 4];   // compacted points (24KB) / reused as fin[64][65]
  __shared__ unsigned acc[T * NROWS];           // delta accumulator [t][row], stride 69 (odd)
  __shared__ int      l_bounds[2];
  __shared__ int      l_cnt;
  __shared__ float    wmax[WAVES];
  __shared__ float    s_scale;

  const int seg  = blockIdx.x;
  const int b    = seg >> 2;     // MAX_CHANNELS == 4
  const int c    = seg & 3;
  const int tid  = threadIdx.x;
  const int lane = tid & 63;
  const int wv   = tid >> 6;

  const float S2D  = SCALE * LOG2E * (2.0f * RADIUS / (RES - 1));  // 4.58 log2-units per bin
  const float invD = (RES - 1) / (2.0f * RADIUS);                  // 31.5
  const float QM   = __builtin_amdgcn_exp2f(-S2D);                 // per-row decay of e

  for (int i = tid; i < T * NROWS; i += THREADS) acc[i] = 0u;

  // wave-parallel 64-ary search for batch bounds (waves 14,15)
  if (wv >= 14) {
    const int tg = b + (wv - 14);
    int lo = 0, len = N;
    while (len > 64) {
      int step = (len + 63) >> 6;
      int p = lo + lane * step;
      bool lt = (p < lo + len) && (index[p] < tg);
      unsigned long long mask = __ballot(lt);
      if (mask) lo += (63 - __clzll(mask)) * step + 1;
      len = min(step, N - lo);
    }
    int p = lo + lane;
    bool ge = (lane < len) && (index[p] >= tg);
    unsigned long long mask = __ballot(ge);
    int ans = mask ? (lo + (int)__builtin_ctzll(mask)) : (lo + len);
    if (lane == 0) l_bounds[wv - 14] = ans;
  }
  __syncthreads();
  const int s0 = l_bounds[0], s1 = l_bounds[1];

  const float v0 = v[0 * T + lane], v1 = v[1 * T + lane], v2 = v[2 * T + lane];
  unsigned* const arow0 = &acc[lane * NROWS];

  for (int base = s0; base < s1; base += CHUNK) {
    const int cnt = min(CHUNK, s1 - base);
    if (tid == 0) l_cnt = 0;
    __syncthreads();
    // ballot-compact channel-c points into lx (CHUNK > THREADS -> strided loop)
    for (int o = tid; o < cnt; o += THREADS) {
      const int pt = base + o;
      const bool match = (channels[pt] == c);
      unsigned long long mask = __ballot(match);
      int wcnt = __popcll(mask);
      int pos = 0;
      if (lane == 0 && wcnt) pos = atomicAdd(&l_cnt, wcnt);
      pos = __shfl(pos, 0);
      if (match) {
        int off = pos + __popcll(mask & ((1ull << lane) - 1ull));
        lx[off * 4 + 0] = x[pt * 3 + 0];
        lx[off * 4 + 1] = x[pt * 3 + 1];
        lx[off * 4 + 2] = x[pt * 3 + 2];
      }
    }
    __syncthreads();
    const int m = l_cnt;
    const float4* lx4 = (const float4*)lx;

    // hot loop: waves stripe points; lane = t; per point: 3 fma + 1 exp2 + 4 rcp + 5 ds_add
    for (int j = wv; j < m; j += WAVES) {
      const float4 p  = lx4[j];                                     // uniform broadcast read
      const float  g  = fmaf(p.x, v0, fmaf(p.y, v1, fmaf(p.z, v2, 0.f))) * invD + invD;
      const int    ifl = (int)floorf(g);
      const int    loc = min(max(ifl - 1, -4), 64);                 // window rows loc..loc+4
      const float  lof = (float)loc;
      float e = __builtin_amdgcn_exp2f(S2D * (g - lof));            // 2^(S2D*(g-loc)), s=1/(1+e)
      unsigned qprev = 0u;
      #pragma unroll
      for (int u = 0; u < 4; ++u) {
        const float s = __builtin_amdgcn_rcpf(1.0f + e);
        unsigned q = (unsigned)fmaf(s, FPSCALE, 0.5f);
        q = max(q, qprev);                                          // monotone guard
        atomicAdd(&arow0[max(loc + u, 0)], q - qprev);
        qprev = q;
        e *= QM;
      }
      atomicAdd(&arow0[loc + 4], FPQ - qprev);                      // tail: +1 for all r >= loc+4
    }
    __syncthreads();
  }

  // per-t inclusive prefix over r of deltas -> value; fin (reuses lx, stride 65)
  float* fin = lx;
  #pragma unroll
  for (int u2 = 0; u2 < 4; ++u2) {
    const int t = (wv << 2) | u2;
    unsigned h = acc[t * NROWS + lane];            // lane = r
    #pragma unroll
    for (int d = 1; d < 64; d <<= 1) {
      unsigned o = __shfl_up(h, (unsigned)d);
      if (lane >= d) h += o;
    }
    fin[lane * 65 + t] = (float)h * FPINV;
  }
  __syncthreads();

  // block max-reduce + normalize + coalesced store
  float vals[4];
  float mx = 0.0f;
  #pragma unroll
  for (int k = 0; k < 4; ++k) {
    const int r = wv + k * 16;                     // flat = tid + k*1024 -> r, t = lane
    vals[k] = fin[r * 65 + lane];
    mx = fmaxf(mx, vals[k]);
  }
  #pragma unroll
  for (int s = 32; s >= 1; s >>= 1) mx = fmaxf(mx, __shfl_xor(mx, s));
  if (lane == 0) wmax[wv] = mx;
  __syncthreads();
  if (tid == 0) {
    float m2 = wmax[0];
    #pragma unroll
    for (int i = 1; i < WAVES; ++i) m2 = fmaxf(m2, wmax[i]);
    s_scale = (m2 > 0.0f) ? 1.0f / m2 : 1.0f;
  }
  __syncthreads();
  const float sc = s_scale;
  float* o = out + (size_t)seg * (RES * T);
  #pragma unroll
  for (int k = 0; k < 4; ++k) o[tid + k * THREADS] = vals[k] * sc;
}

extern "C" void kernel_launch(void* const* d_in, const int* in_sizes, int n_in,
                              void* d_out, int out_size, void* d_ws, size_t ws_size,
                              hipStream_t stream) {
  const float* x        = (const float*)d_in[0];
  const float* v        = (const float*)d_in[1];
  const int*   index    = (const int*)d_in[2];
  const int*   channels = (const int*)d_in[3];
  float*       out      = (float*)d_out;
  const int N    = in_sizes[2];              // 32768
  const int nseg = out_size / (RES * T);     // 128

  hipLaunchKernelGGL(ect_main, dim3(nseg), dim3(THREADS), 0, stream,
                     x, v, index, channels, out, N);
}

// Round 11
// 16.551 us; speedup vs baseline: 2.4574x; 1.0274x over previous
//
#include <hip/hip_runtime.h>

// ECT: out[b,c,r,t] = sum_{n in (b,c)} sigmoid(SCALE*(lin[r] - x[n].v[:,t])), max-normalized per (b,c).
// r10: r9 hot loop + epilogue verbatim; front-end rebuilt: NO search phase. Threads speculatively
// load a +-512-margin window (index,channels,x) into registers first (HBM latency hides under
// acc zeroing), ballot-compact with predicate index==b && ch==c, coverage verified from loaded
// boundary values, full-scan fallback for the (never-hit) uncovered case.

constexpr int T   = 64;
constexpr int RES = 64;
constexpr float RADIUS = 1.0f;
constexpr float SCALE  = 100.0f;
constexpr float LOG2E  = 1.44269504088896340736f;

#define THREADS 1024
#define WAVES   16
#define NROWS   69                 // delta rows 0..68 (loc in [-4,64], tail at loc+4)
#define LXCAP   1040               // compacted-point capacity (lx = 4160 floats, also fin 64x65)
#define WMARG   512                // speculative window margin (~5.7 sigma)
#define FPSCALE 1048576.0f         // 2^20
#define FPQ     1048576u
#define FPINV   (1.0f / 1048576.0f)

__global__ __launch_bounds__(THREADS) void ect_main(
    const float* __restrict__ x, const float* __restrict__ v,
    const int* __restrict__ index, const int* __restrict__ channels,
    float* __restrict__ out, int N, int ppb)
{
  __shared__ alignas(16) float lx[4160];   // compacted points (float4) / reused as fin[64][65]
  __shared__ unsigned acc[T * NROWS];      // delta accumulator [t][row], stride 69 (odd)
  __shared__ int      l_cnt;
  __shared__ int      l_flag;
  __shared__ float    wmax[WAVES];
  __shared__ float    s_scale;

  const int seg  = blockIdx.x;
  const int b    = seg >> 2;     // MAX_CHANNELS == 4
  const int c    = seg & 3;
  const int tid  = threadIdx.x;
  const int lane = tid & 63;
  const int wv   = tid >> 6;

  const float S2D  = SCALE * LOG2E * (2.0f * RADIUS / (RES - 1));  // 4.58 log2-units/bin
  const float invD = (RES - 1) / (2.0f * RADIUS);                  // 31.5
  const float QM   = __builtin_amdgcn_exp2f(-S2D);                 // per-row decay of e

  // ---- speculative window loads FIRST (latency hides under zeroing) ----
  const int lo_w = max(0, b * ppb - WMARG);
  const int hi_w = min(N, (b + 1) * ppb + WMARG);
  const int pt0  = lo_w + tid;
  const int pt1  = lo_w + THREADS + tid;
  int i0 = -1, c0 = -1, i1 = -1, c1 = -1;
  float x0 = 0.f, y0 = 0.f, z0 = 0.f, x1 = 0.f, y1 = 0.f, z1 = 0.f;
  if (pt0 < hi_w) {
    i0 = index[pt0]; c0 = channels[pt0];
    x0 = x[pt0 * 3 + 0]; y0 = x[pt0 * 3 + 1]; z0 = x[pt0 * 3 + 2];
  }
  if (pt1 < hi_w) {
    i1 = index[pt1]; c1 = channels[pt1];
    x1 = x[pt1 * 3 + 0]; y1 = x[pt1 * 3 + 1]; z1 = x[pt1 * 3 + 2];
  }
  const float v0 = v[0 * T + lane], v1 = v[1 * T + lane], v2 = v[2 * T + lane];

  if (tid == 0) { l_cnt = 0; l_flag = 0; }
  for (int i = tid; i < T * NROWS; i += THREADS) acc[i] = 0u;
  __syncthreads();

  // ---- coverage verification from loaded boundary values ----
  if (pt0 == lo_w && lo_w > 0 && i0 >= b) atomicOr(&l_flag, 1);           // batch may start left
  if (pt0 == hi_w - 1 && hi_w < N && i0 <= b) atomicOr(&l_flag, 1);       // batch may end right
  if (pt1 == hi_w - 1 && hi_w < N && i1 <= b) atomicOr(&l_flag, 1);

  // ---- ballot-compact from registers ----
  {
    const bool m0 = (pt0 < hi_w) && (i0 == b) && (c0 == c);
    unsigned long long mk = __ballot(m0);
    int wc = __popcll(mk), pos = 0;
    if (lane == 0 && wc) pos = atomicAdd(&l_cnt, wc);
    pos = __shfl(pos, 0);
    if (m0) {
      int off = min(pos + __popcll(mk & ((1ull << lane) - 1ull)), LXCAP - 1);
      lx[off * 4 + 0] = x0; lx[off * 4 + 1] = y0; lx[off * 4 + 2] = z0;
    }
    const bool m1 = (pt1 < hi_w) && (i1 == b) && (c1 == c);
    mk = __ballot(m1);
    wc = __popcll(mk); pos = 0;
    if (lane == 0 && wc) pos = atomicAdd(&l_cnt, wc);
    pos = __shfl(pos, 0);
    if (m1) {
      int off = min(pos + __popcll(mk & ((1ull << lane) - 1ull)), LXCAP - 1);
      lx[off * 4 + 0] = x1; lx[off * 4 + 1] = y1; lx[off * 4 + 2] = z1;
    }
  }
  __syncthreads();

  // ---- fallback: scan outside the window if coverage failed (never for this input) ----
  if (l_flag) {
    for (int p = tid; p < N; p += THREADS) {
      const bool inw = (p >= lo_w) && (p < hi_w);
      const bool mt  = !inw && (index[p] == b) && (channels[p] == c);
      unsigned long long mk = __ballot(mt);
      int wc = __popcll(mk), pos = 0;
      if (lane == 0 && wc) pos = atomicAdd(&l_cnt, wc);
      pos = __shfl(pos, 0);
      if (mt) {
        int off = min(pos + __popcll(mk & ((1ull << lane) - 1ull)), LXCAP - 1);
        lx[off * 4 + 0] = x[p * 3 + 0]; lx[off * 4 + 1] = x[p * 3 + 1]; lx[off * 4 + 2] = x[p * 3 + 2];
      }
    }
    __syncthreads();
  }
  const int m = min(l_cnt, LXCAP);
  const float4* lx4 = (const float4*)lx;
  unsigned* const arow0 = &acc[lane * NROWS];

  // ---- hot loop (r9 verbatim): waves stripe points; lane = t ----
  for (int j = wv; j < m; j += WAVES) {
    const float4 p  = lx4[j];                                     // uniform broadcast read
    const float  g  = fmaf(p.x, v0, fmaf(p.y, v1, fmaf(p.z, v2, 0.f))) * invD + invD;
    const int    ifl = (int)floorf(g);
    const int    loc = min(max(ifl - 1, -4), 64);                 // window rows loc..loc+4
    const float  lof = (float)loc;
    float e = __builtin_amdgcn_exp2f(S2D * (g - lof));
    unsigned qprev = 0u;
    #pragma unroll
    for (int u = 0; u < 4; ++u) {
      const float s = __builtin_amdgcn_rcpf(1.0f + e);
      unsigned q = (unsigned)fmaf(s, FPSCALE, 0.5f);
      q = max(q, qprev);                                          // monotone guard
      atomicAdd(&arow0[max(loc + u, 0)], q - qprev);
      qprev = q;
      e *= QM;
    }
    atomicAdd(&arow0[loc + 4], FPQ - qprev);                      // tail: +1 for all r >= loc+4
  }
  __syncthreads();

  // ---- epilogue (r9 verbatim): prefix over r, max-normalize, store ----
  float* fin = lx;
  #pragma unroll
  for (int u2 = 0; u2 < 4; ++u2) {
    const int t = (wv << 2) | u2;
    unsigned h = acc[t * NROWS + lane];            // lane = r
    #pragma unroll
    for (int d = 1; d < 64; d <<= 1) {
      unsigned o = __shfl_up(h, (unsigned)d);
      if (lane >= d) h += o;
    }
    fin[lane * 65 + t] = (float)h * FPINV;
  }
  __syncthreads();

  float vals[4];
  float mx = 0.0f;
  #pragma unroll
  for (int k = 0; k < 4; ++k) {
    const int r = wv + k * 16;
    vals[k] = fin[r * 65 + lane];
    mx = fmaxf(mx, vals[k]);
  }
  #pragma unroll
  for (int s = 32; s >= 1; s >>= 1) mx = fmaxf(mx, __shfl_xor(mx, s));
  if (lane == 0) wmax[wv] = mx;
  __syncthreads();
  if (tid == 0) {
    float m2 = wmax[0];
    #pragma unroll
    for (int i = 1; i < WAVES; ++i) m2 = fmaxf(m2, wmax[i]);
    s_scale = (m2 > 0.0f) ? 1.0f / m2 : 1.0f;
  }
  __syncthreads();
  const float sc = s_scale;
  float* o = out + (size_t)seg * (RES * T);
  #pragma unroll
  for (int k = 0; k < 4; ++k) o[tid + k * THREADS] = vals[k] * sc;
}

extern "C" void kernel_launch(void* const* d_in, const int* in_sizes, int n_in,
                              void* d_out, int out_size, void* d_ws, size_t ws_size,
                              hipStream_t stream) {
  const float* x        = (const float*)d_in[0];
  const float* v        = (const float*)d_in[1];
  const int*   index    = (const int*)d_in[2];
  const int*   channels = (const int*)d_in[3];
  float*       out      = (float*)d_out;
  const int N    = in_sizes[2];              // 32768
  const int nseg = out_size / (RES * T);     // 128
  const int ppb  = N / (nseg / 4);           // points per batch estimate (1024)

  hipLaunchKernelGGL(ect_main, dim3(nseg), dim3(THREADS), 0, stream,
                     x, v, index, channels, out, N, ppb);
}